// Round 1
// baseline (409.533 us; speedup 1.0000x reference)
//
#include <hip/hip_runtime.h>
#include <hip/hip_bf16.h>

// Problem constants: B=4, S=4096, D=1024, R=64
#define M_TOT 16384   // B*S
#define DK    1024
#define RN    64
#define SQ_S  4096

typedef __attribute__((ext_vector_type(8))) short  short8;   // 8 bf16 (4 VGPRs)
typedef __attribute__((ext_vector_type(4))) float  f32x4;

__device__ __forceinline__ unsigned short f2bf(float f) {
    unsigned u = __float_as_uint(f);
    return (unsigned short)((u + 0x7fffu + ((u >> 16) & 1u)) >> 16);  // RNE
}
__device__ __forceinline__ float bf2f(unsigned short h) {
    return __uint_as_float((unsigned)h << 16);
}

// ---------------------------------------------------------------------------
// prep: proj [D][R] fp32  ->  projT_hi / projT_lo [R][D] bf16-bits
// ---------------------------------------------------------------------------
__global__ __launch_bounds__(256) void prep_kernel(
        const float* __restrict__ proj,
        unsigned short* __restrict__ pTh,
        unsigned short* __restrict__ pTl) {
    int idx = blockIdx.x * 256 + threadIdx.x;      // 0 .. R*D-1
    int r = idx >> 10;            // / DK
    int k = idx & 1023;           // % DK
    float v = proj[k * RN + r];
    unsigned short hi = f2bf(v);
    pTh[idx] = hi;
    pTl[idx] = f2bf(v - bf2f(hi));
}

// ---------------------------------------------------------------------------
// phase 1: p = x @ proj  (M=16384, K=1024, N=64), bf16 split-3 MFMA.
// Each wave: 16 rows, full K. Writes p_hi/p_lo (bf16 bits) + sq (fp32).
// ---------------------------------------------------------------------------
__global__ __launch_bounds__(256) void phase1_kernel(
        const float* __restrict__ x,
        const unsigned short* __restrict__ pTh,
        const unsigned short* __restrict__ pTl,
        unsigned short* __restrict__ p_hi,
        unsigned short* __restrict__ p_lo,
        float* __restrict__ sq) {
    const int tid  = threadIdx.x;
    const int wave = tid >> 6;
    const int lane = tid & 63;
    const int lr   = lane & 15;   // row within 16-tile (A) / col (B)
    const int lg   = lane >> 4;   // k-subgroup (8 elements each)

    const long m0   = (long)blockIdx.x * 64 + wave * 16;
    const float* xrow = x + (m0 + lr) * DK + lg * 8;

    f32x4 acc[4] = {f32x4{0,0,0,0}, f32x4{0,0,0,0}, f32x4{0,0,0,0}, f32x4{0,0,0,0}};

    for (int kc = 0; kc < DK / 32; ++kc) {
        // --- A fragment: 8 fp32 from x, split into hi/lo bf16 ---
        f32x4 a0 = *(const f32x4*)(xrow + kc * 32);
        f32x4 a1 = *(const f32x4*)(xrow + kc * 32 + 4);
        short8 ah, al;
        #pragma unroll
        for (int i = 0; i < 4; ++i) {
            unsigned short h0 = f2bf(a0[i]);
            ah[i] = (short)h0;
            al[i] = (short)f2bf(a0[i] - bf2f(h0));
            unsigned short h1 = f2bf(a1[i]);
            ah[i + 4] = (short)h1;
            al[i + 4] = (short)f2bf(a1[i] - bf2f(h1));
        }
        // --- B fragments (projT, k-contiguous) + MFMA, 4 col-tiles ---
        #pragma unroll
        for (int cj = 0; cj < 4; ++cj) {
            long bo = (long)(cj * 16 + lr) * DK + kc * 32 + lg * 8;
            short8 bh = *(const short8*)(pTh + bo);
            short8 bl = *(const short8*)(pTl + bo);
            f32x4 c = acc[cj];
            c = __builtin_amdgcn_mfma_f32_16x16x32_bf16(ah, bh, c, 0, 0, 0);
            c = __builtin_amdgcn_mfma_f32_16x16x32_bf16(ah, bl, c, 0, 0, 0);
            c = __builtin_amdgcn_mfma_f32_16x16x32_bf16(al, bh, c, 0, 0, 0);
            acc[cj] = c;
        }
    }

    // Epilogue: C/D layout col=lane&15, row=(lane>>4)*4+j  [m89-verified]
    #pragma unroll
    for (int j = 0; j < 4; ++j) {
        const long m = m0 + lg * 4 + j;
        float ssum = 0.f;
        #pragma unroll
        for (int cj = 0; cj < 4; ++cj) {
            float v = acc[cj][j];
            unsigned short hi = f2bf(v);
            p_hi[m * RN + cj * 16 + lr] = hi;
            p_lo[m * RN + cj * 16 + lr] = f2bf(v - bf2f(hi));
            ssum += v * v;
        }
        // reduce the 64 cols of row m across the 16 lanes of this group
        ssum += __shfl_xor(ssum, 1);
        ssum += __shfl_xor(ssum, 2);
        ssum += __shfl_xor(ssum, 4);
        ssum += __shfl_xor(ssum, 8);
        if (lr == 0) sq[m] = ssum;
    }
}

// ---------------------------------------------------------------------------
// phase 2: per batch, dist[s,t] = relu(sq[s]+sq[t] - 2 * p[s].p[t])
// 128x128 tile per block, 4 waves (2x2) of 64x64 each. K=64.
// ---------------------------------------------------------------------------
__global__ __launch_bounds__(256) void phase2_kernel(
        const unsigned short* __restrict__ p_hi,
        const unsigned short* __restrict__ p_lo,
        const float* __restrict__ sq,
        float* __restrict__ out) {
    const int b  = blockIdx.z;
    const long s0 = (long)blockIdx.y * 128;
    const long t0 = (long)blockIdx.x * 128;
    const int tid  = threadIdx.x;
    const int wave = tid >> 6;
    const int lane = tid & 63;
    const int wr = wave >> 1, wc = wave & 1;
    const int lr = lane & 15, lg = lane >> 4;

    const unsigned short* ph  = p_hi + (long)b * SQ_S * RN;
    const unsigned short* pl  = p_lo + (long)b * SQ_S * RN;
    const float*          sqb = sq   + (long)b * SQ_S;

    f32x4 acc[4][4];
    #pragma unroll
    for (int i = 0; i < 4; ++i)
        #pragma unroll
        for (int j = 0; j < 4; ++j) acc[i][j] = f32x4{0, 0, 0, 0};

    const long arow = s0 + wr * 64 + lr;
    const long brow = t0 + wc * 64 + lr;

    #pragma unroll
    for (int kc = 0; kc < 2; ++kc) {
        short8 ah[4], al[4], bh[4], bl[4];
        #pragma unroll
        for (int i = 0; i < 4; ++i) {
            long ao = (arow + i * 16) * RN + kc * 32 + lg * 8;
            ah[i] = *(const short8*)(ph + ao);
            al[i] = *(const short8*)(pl + ao);
            long bo = (brow + i * 16) * RN + kc * 32 + lg * 8;
            bh[i] = *(const short8*)(ph + bo);
            bl[i] = *(const short8*)(pl + bo);
        }
        #pragma unroll
        for (int ai = 0; ai < 4; ++ai)
            #pragma unroll
            for (int bj = 0; bj < 4; ++bj) {
                f32x4 c = acc[ai][bj];
                c = __builtin_amdgcn_mfma_f32_16x16x32_bf16(ah[ai], bh[bj], c, 0, 0, 0);
                c = __builtin_amdgcn_mfma_f32_16x16x32_bf16(ah[ai], bl[bj], c, 0, 0, 0);
                c = __builtin_amdgcn_mfma_f32_16x16x32_bf16(al[ai], bh[bj], c, 0, 0, 0);
                acc[ai][bj] = c;
            }
    }

    // Epilogue: dist = relu(sq_s + sq_t - 2*cross)
    float sqt[4];
    #pragma unroll
    for (int bj = 0; bj < 4; ++bj) sqt[bj] = sqb[t0 + wc * 64 + bj * 16 + lr];

    float* outb = out + (long)b * SQ_S * SQ_S;
    #pragma unroll
    for (int ai = 0; ai < 4; ++ai) {
        #pragma unroll
        for (int j = 0; j < 4; ++j) {
            long srow = s0 + wr * 64 + ai * 16 + lg * 4 + j;
            float sqs = sqb[srow];
            float* orow = outb + srow * SQ_S + t0 + wc * 64;
            #pragma unroll
            for (int bj = 0; bj < 4; ++bj) {
                float d = sqs + sqt[bj] - 2.0f * acc[ai][bj][j];
                orow[bj * 16 + lr] = fmaxf(d, 0.0f);
            }
        }
    }
}

// ---------------------------------------------------------------------------
extern "C" void kernel_launch(void* const* d_in, const int* in_sizes, int n_in,
                              void* d_out, int out_size, void* d_ws, size_t ws_size,
                              hipStream_t stream) {
    const float* x    = (const float*)d_in[0];   // [B,S,D] fp32
    const float* proj = (const float*)d_in[1];   // [D,R]  fp32
    float* out = (float*)d_out;                  // [B,S,S] fp32

    // Workspace layout (all 16B-aligned):
    //   projT_hi: R*D ushort = 128 KiB
    //   projT_lo: R*D ushort = 128 KiB
    //   p_hi:     M*R ushort = 2 MiB
    //   p_lo:     M*R ushort = 2 MiB
    //   sq:       M float    = 64 KiB
    unsigned short* pTh  = (unsigned short*)d_ws;
    unsigned short* pTl  = pTh + RN * DK;
    unsigned short* p_hi = pTl + RN * DK;
    unsigned short* p_lo = p_hi + (long)M_TOT * RN;
    float*          sqp  = (float*)(p_lo + (long)M_TOT * RN);

    prep_kernel<<<(RN * DK) / 256, 256, 0, stream>>>(proj, pTh, pTl);
    phase1_kernel<<<M_TOT / 64, 256, 0, stream>>>(x, pTh, pTl, p_hi, p_lo, sqp);
    phase2_kernel<<<dim3(SQ_S / 128, SQ_S / 128, 4), 256, 0, stream>>>(p_hi, p_lo, sqp, out);
}

// Round 2
// 374.237 us; speedup vs baseline: 1.0943x; 1.0943x over previous
//
#include <hip/hip_runtime.h>
#include <hip/hip_bf16.h>

// Problem constants: B=4, S=4096, D=1024, R=64
#define M_TOT 16384   // B*S
#define DK    1024
#define RN    64
#define SQ_S  4096

typedef __attribute__((ext_vector_type(8))) short  short8;   // 8 bf16 (4 VGPRs)
typedef __attribute__((ext_vector_type(4))) float  f32x4;

__device__ __forceinline__ unsigned short f2bf(float f) {
    unsigned u = __float_as_uint(f);
    return (unsigned short)((u + 0x7fffu + ((u >> 16) & 1u)) >> 16);  // RNE
}
__device__ __forceinline__ float bf2f(unsigned short h) {
    return __uint_as_float((unsigned)h << 16);
}

// ---------------------------------------------------------------------------
// prep: proj [D][R] fp32  ->  projT_hi / projT_lo [R][D] bf16-bits
// (validated round-1; tiny kernel, 256 KiB in / 512 KiB out)
// ---------------------------------------------------------------------------
__global__ __launch_bounds__(256) void prep_kernel(
        const float* __restrict__ proj,
        unsigned short* __restrict__ pTh,
        unsigned short* __restrict__ pTl) {
    int idx = blockIdx.x * 256 + threadIdx.x;      // 0 .. R*D-1
    int r = idx >> 10;            // / DK
    int k = idx & 1023;           // % DK
    float v = proj[k * RN + r];
    unsigned short hi = f2bf(v);
    pTh[idx] = hi;
    pTl[idx] = f2bf(v - bf2f(hi));
}

// ---------------------------------------------------------------------------
// phase 1: p = x @ proj  (M=16384, K=1024, N=64), bf16 split-3 MFMA.
// NEW: K-split across the block's 4 waves (256 deep each) + LDS reduction.
// Grid 1024 blocks (16 rows each) -> 4 waves/SIMD occupancy (was 1).
// ---------------------------------------------------------------------------
__global__ __launch_bounds__(256) void phase1_kernel(
        const float* __restrict__ x,
        const unsigned short* __restrict__ pTh,
        const unsigned short* __restrict__ pTl,
        unsigned short* __restrict__ p_hi,
        unsigned short* __restrict__ p_lo,
        float* __restrict__ sq) {
    const int tid  = threadIdx.x;
    const int wave = tid >> 6;
    const int lane = tid & 63;
    const int lr   = lane & 15;   // row within 16-tile (A) / col (B)
    const int lg   = lane >> 4;   // k-subgroup (8 elements each)

    const long m0    = (long)blockIdx.x * 16;
    const int  kbase = wave * 256;                 // this wave's K slice
    const float* xrow = x + (m0 + lr) * DK + kbase + lg * 8;

    f32x4 acc[4] = {f32x4{0,0,0,0}, f32x4{0,0,0,0}, f32x4{0,0,0,0}, f32x4{0,0,0,0}};

    #pragma unroll 2
    for (int kc = 0; kc < 8; ++kc) {
        // --- A fragment: 8 fp32 from x, split into hi/lo bf16 (RNE) ---
        f32x4 a0 = *(const f32x4*)(xrow + kc * 32);
        f32x4 a1 = *(const f32x4*)(xrow + kc * 32 + 4);
        short8 ah, al;
        #pragma unroll
        for (int i = 0; i < 4; ++i) {
            unsigned short h0 = f2bf(a0[i]);
            ah[i] = (short)h0;
            al[i] = (short)f2bf(a0[i] - bf2f(h0));
            unsigned short h1 = f2bf(a1[i]);
            ah[i + 4] = (short)h1;
            al[i + 4] = (short)f2bf(a1[i] - bf2f(h1));
        }
        // --- B fragments (projT, k-contiguous, L2-hot) + split-3 MFMA ---
        #pragma unroll
        for (int cj = 0; cj < 4; ++cj) {
            long bo = (long)(cj * 16 + lr) * DK + kbase + kc * 32 + lg * 8;
            short8 bh = *(const short8*)(pTh + bo);
            short8 bl = *(const short8*)(pTl + bo);
            f32x4 c = acc[cj];
            c = __builtin_amdgcn_mfma_f32_16x16x32_bf16(ah, bh, c, 0, 0, 0);
            c = __builtin_amdgcn_mfma_f32_16x16x32_bf16(ah, bl, c, 0, 0, 0);
            c = __builtin_amdgcn_mfma_f32_16x16x32_bf16(al, bh, c, 0, 0, 0);
            acc[cj] = c;
        }
    }

    // --- cross-wave K reduction via LDS (pad 17: 2-way bank alias = free) ---
    __shared__ float red[4][64][17];
    #pragma unroll
    for (int cj = 0; cj < 4; ++cj)
        #pragma unroll
        for (int j = 0; j < 4; ++j)
            red[wave][lane][cj * 4 + j] = acc[cj][j];
    __syncthreads();

    if (wave == 0) {
        // Epilogue identical to validated round-1 (C/D: col=lane&15,
        // row=(lane>>4)*4+j), sourced from the LDS partial sums.
        #pragma unroll
        for (int j = 0; j < 4; ++j) {
            const long m = m0 + lg * 4 + j;
            float ssum = 0.f;
            #pragma unroll
            for (int cj = 0; cj < 4; ++cj) {
                const int sl = cj * 4 + j;
                float v = red[0][lane][sl] + red[1][lane][sl]
                        + red[2][lane][sl] + red[3][lane][sl];
                unsigned short hi = f2bf(v);
                p_hi[m * RN + cj * 16 + lr] = hi;
                p_lo[m * RN + cj * 16 + lr] = f2bf(v - bf2f(hi));
                ssum += v * v;
            }
            ssum += __shfl_xor(ssum, 1);
            ssum += __shfl_xor(ssum, 2);
            ssum += __shfl_xor(ssum, 4);
            ssum += __shfl_xor(ssum, 8);
            if (lr == 0) sq[m] = ssum;
        }
    }
}

// ---------------------------------------------------------------------------
// phase 2: per batch, dist[s,t] = relu(sq[s]+sq[t] - 2 * p[s].p[t])
// 128x128 tile per block, 4 waves (2x2) of 64x64 each. K=64.
// NEW: A-operand <- t rows, B-operand <- s rows, so each lane's 4 acc
// elements are 4 CONSECUTIVE t columns -> one dwordx4 nontemporal store
// per 16x16 tile (was 4 scalar dword stores).
// ---------------------------------------------------------------------------
__global__ __launch_bounds__(256) void phase2_kernel(
        const unsigned short* __restrict__ p_hi,
        const unsigned short* __restrict__ p_lo,
        const float* __restrict__ sq,
        float* __restrict__ out) {
    const int b  = blockIdx.z;
    const long s0 = (long)blockIdx.y * 128;
    const long t0 = (long)blockIdx.x * 128;
    const int tid  = threadIdx.x;
    const int wave = tid >> 6;
    const int lane = tid & 63;
    const int ws = wave >> 1, wt = wave & 1;   // s-half / t-half of the 128x128 tile
    const int lr = lane & 15, lg = lane >> 4;

    const unsigned short* ph  = p_hi + (long)b * SQ_S * RN;
    const unsigned short* pl  = p_lo + (long)b * SQ_S * RN;
    const float*          sqb = sq   + (long)b * SQ_S;

    f32x4 acc[4][4];   // [ai: t-tile][bj: s-tile]
    #pragma unroll
    for (int i = 0; i < 4; ++i)
        #pragma unroll
        for (int j = 0; j < 4; ++j) acc[i][j] = f32x4{0, 0, 0, 0};

    const long trow = t0 + wt * 64 + lr;   // A-operand rows (t side)
    const long srow = s0 + ws * 64 + lr;   // B-operand rows (s side)

    #pragma unroll
    for (int kc = 0; kc < 2; ++kc) {
        short8 th_[4], tl_[4], sh_[4], sl_[4];
        #pragma unroll
        for (int i = 0; i < 4; ++i) {
            long ao = (trow + i * 16) * RN + kc * 32 + lg * 8;
            th_[i] = *(const short8*)(ph + ao);
            tl_[i] = *(const short8*)(pl + ao);
            long bo = (srow + i * 16) * RN + kc * 32 + lg * 8;
            sh_[i] = *(const short8*)(ph + bo);
            sl_[i] = *(const short8*)(pl + bo);
        }
        #pragma unroll
        for (int ai = 0; ai < 4; ++ai)
            #pragma unroll
            for (int bj = 0; bj < 4; ++bj) {
                f32x4 c = acc[ai][bj];
                c = __builtin_amdgcn_mfma_f32_16x16x32_bf16(th_[ai], sh_[bj], c, 0, 0, 0);
                c = __builtin_amdgcn_mfma_f32_16x16x32_bf16(th_[ai], sl_[bj], c, 0, 0, 0);
                c = __builtin_amdgcn_mfma_f32_16x16x32_bf16(tl_[ai], sh_[bj], c, 0, 0, 0);
                acc[ai][bj] = c;
            }
    }

    // Epilogue: dist = relu(sq_s + sq_t - 2*cross), vectorized stores.
    f32x4 sqt[4];
    #pragma unroll
    for (int ai = 0; ai < 4; ++ai)
        sqt[ai] = *(const f32x4*)(sqb + t0 + wt * 64 + ai * 16 + lg * 4);
    float sqs[4];
    #pragma unroll
    for (int bj = 0; bj < 4; ++bj)
        sqs[bj] = sqb[s0 + ws * 64 + bj * 16 + lr];

    float* outb = out + (long)b * SQ_S * SQ_S;
    #pragma unroll
    for (int bj = 0; bj < 4; ++bj) {
        const long s = s0 + ws * 64 + bj * 16 + lr;
        float* orow = outb + s * SQ_S + t0 + wt * 64;
        #pragma unroll
        for (int ai = 0; ai < 4; ++ai) {
            f32x4 v;
            #pragma unroll
            for (int j = 0; j < 4; ++j)
                v[j] = fmaxf(sqs[bj] + sqt[ai][j] - 2.0f * acc[ai][bj][j], 0.0f);
            __builtin_nontemporal_store(v, (f32x4*)(orow + ai * 16 + lg * 4));
        }
    }
}

// ---------------------------------------------------------------------------
extern "C" void kernel_launch(void* const* d_in, const int* in_sizes, int n_in,
                              void* d_out, int out_size, void* d_ws, size_t ws_size,
                              hipStream_t stream) {
    const float* x    = (const float*)d_in[0];   // [B,S,D] fp32
    const float* proj = (const float*)d_in[1];   // [D,R]  fp32
    float* out = (float*)d_out;                  // [B,S,S] fp32

    // Workspace layout (all 16B-aligned):
    //   projT_hi: R*D ushort = 128 KiB
    //   projT_lo: R*D ushort = 128 KiB
    //   p_hi:     M*R ushort = 2 MiB
    //   p_lo:     M*R ushort = 2 MiB
    //   sq:       M float    = 64 KiB
    unsigned short* pTh  = (unsigned short*)d_ws;
    unsigned short* pTl  = pTh + RN * DK;
    unsigned short* p_hi = pTl + RN * DK;
    unsigned short* p_lo = p_hi + (long)M_TOT * RN;
    float*          sqp  = (float*)(p_lo + (long)M_TOT * RN);

    prep_kernel<<<(RN * DK) / 256, 256, 0, stream>>>(proj, pTh, pTl);
    phase1_kernel<<<M_TOT / 16, 256, 0, stream>>>(x, pTh, pTl, p_hi, p_lo, sqp);
    phase2_kernel<<<dim3(SQ_S / 128, SQ_S / 128, 4), 256, 0, stream>>>(p_hi, p_lo, sqp, out);
}